// Round 1
// baseline (1370.919 us; speedup 1.0000x reference)
//
#include <hip/hip_runtime.h>
#include <cmath>

#define NN 20000
#define FF 128
#define HH 128
#define CCD 4
#define EE 32768
#define RR 8
#define DMSG 273  // 2*F + C*C + ED

#define OUT_X (NN*FF)            // 2,560,000
#define OUT_M (NN*FF + NN*12)    // 2,800,000

__device__ __forceinline__ float silu_f(float x) {
    return x / (1.0f + __expf(-x));
}

// ---- generic 32x128 tile GEMM: acc[e 4][j 4], 256 threads ----
// sIn: 32 x K (leading dim LDA, LDA%4==0), B: K x 128 row-major (global)
template<int K, int LDA>
__device__ __forceinline__ void gemm_acc(const float* __restrict__ B,
                                         const float* sIn, int tid,
                                         float acc[4][4])
{
    const int tx = tid & 31;   // j base
    const int ty = tid >> 5;   // edge group 0..7
#pragma unroll
    for (int ee = 0; ee < 4; ee++)
#pragma unroll
        for (int jj = 0; jj < 4; jj++) acc[ee][jj] = 0.f;

    constexpr int K4 = K & ~3;
    const float* aBase = sIn + (ty * 4) * LDA;
    for (int k4 = 0; k4 < K4; k4 += 4) {
        float4 av[4];
#pragma unroll
        for (int ee = 0; ee < 4; ee++)
            av[ee] = *(const float4*)(aBase + ee * LDA + k4);
#pragma unroll
        for (int kk = 0; kk < 4; kk++) {
            const float* brow = B + (size_t)(k4 + kk) * 128 + tx;
            float b0 = brow[0], b1 = brow[32], b2 = brow[64], b3 = brow[96];
#pragma unroll
            for (int ee = 0; ee < 4; ee++) {
                float a = reinterpret_cast<const float*>(&av[ee])[kk];
                acc[ee][0] = fmaf(a, b0, acc[ee][0]);
                acc[ee][1] = fmaf(a, b1, acc[ee][1]);
                acc[ee][2] = fmaf(a, b2, acc[ee][2]);
                acc[ee][3] = fmaf(a, b3, acc[ee][3]);
            }
        }
    }
    if constexpr ((K & 3) != 0) {
        for (int k = K4; k < K; k++) {
            const float* brow = B + (size_t)k * 128 + tx;
            float b0 = brow[0], b1 = brow[32], b2 = brow[64], b3 = brow[96];
#pragma unroll
            for (int ee = 0; ee < 4; ee++) {
                float a = aBase[ee * LDA + k];
                acc[ee][0] = fmaf(a, b0, acc[ee][0]);
                acc[ee][1] = fmaf(a, b1, acc[ee][1]);
                acc[ee][2] = fmaf(a, b2, acc[ee][2]);
                acc[ee][3] = fmaf(a, b3, acc[ee][3]);
            }
        }
    }
}

__device__ __forceinline__ void store_act(float acc[4][4], const float* __restrict__ bias,
                                          float* sOut, int ldOut, int tid, bool dosilu)
{
    const int tx = tid & 31, ty = tid >> 5;
#pragma unroll
    for (int ee = 0; ee < 4; ee++)
#pragma unroll
        for (int jj = 0; jj < 4; jj++) {
            int j = tx + 32 * jj;
            float v = acc[ee][jj] + bias[j];
            if (dosilu) v = silu_f(v);
            sOut[(ty * 4 + ee) * ldOut + j] = v;
        }
}

// ---- kernel 1: per-relation radial norm (sum over edges of radial^2) ----
__global__ __launch_bounds__(256) void k_norm(const float* __restrict__ coord,
                                              const int* __restrict__ edges,
                                              float* __restrict__ nsq)
{
    const int r = blockIdx.x;
    const int chunk = blockIdx.y;
    const int tid = threadIdx.x;
    const int* rows = edges + r * 2 * EE;
    const int* cols = rows + EE;
    float acc[16];
#pragma unroll
    for (int i = 0; i < 16; i++) acc[i] = 0.f;
    const int e0 = chunk * 1024;
    for (int e = e0 + tid; e < e0 + 1024; e += 256) {
        int ro = rows[e], co = cols[e];
        float cd[12];
        const float* cr = coord + (size_t)ro * 12;
        const float* cc = coord + (size_t)co * 12;
#pragma unroll
        for (int i = 0; i < 12; i++) cd[i] = cr[i] - cc[i];
#pragma unroll
        for (int c = 0; c < 4; c++)
#pragma unroll
            for (int d = 0; d < 4; d++) {
                float v = cd[c*3]*cd[d*3] + cd[c*3+1]*cd[d*3+1] + cd[c*3+2]*cd[d*3+2];
                acc[c*4+d] += v * v;
            }
    }
#pragma unroll
    for (int i = 0; i < 16; i++) {
        float v = acc[i];
        for (int off = 32; off; off >>= 1) v += __shfl_down(v, off, 64);
        if ((tid & 63) == 0) atomicAdd(&nsq[r * 16 + i], v);
    }
}

__global__ void k_invnorm(const float* __restrict__ nsq, float* __restrict__ inv_norm)
{
    int i = threadIdx.x;
    if (i < RR * 16) {
        float n = sqrtf(nsq[i]);
        inv_norm[i] = 1.0f / fmaxf(n, 1e-12f);
    }
}

// ---- kernel 2: message MLP + coord phi + scatters ----
__global__ __launch_bounds__(256) void k_msg(
    const float* __restrict__ h, const float* __restrict__ coord,
    const float* __restrict__ eattr, const int* __restrict__ edges,
    const float* __restrict__ inv_norm,
    const float* __restrict__ Wm1, const float* __restrict__ bm1,
    const float* __restrict__ Wm2, const float* __restrict__ bm2,
    const float* __restrict__ Wc1, const float* __restrict__ bc1,
    const float* __restrict__ Wc2, const float* __restrict__ Wrel,
    float* __restrict__ sAccum, float* __restrict__ cnt, float* __restrict__ agg)
{
    __shared__ __align__(16) float shA[32 * 276];  // msg tile; later ef (ld 132)
    __shared__ __align__(16) float shT[32 * 132];  // t1; later hid
    __shared__ float shCd[32 * 12];
    __shared__ float shPhi[32 * 4];
    __shared__ int shRow[32], shCol[32];
    __shared__ float shInv[16];

    const int tid = threadIdx.x;
    const int r = blockIdx.y;
    const int e0 = blockIdx.x * 32;

    if (tid < 32) shRow[tid] = edges[r * 2 * EE + e0 + tid];
    else if (tid < 64) shCol[tid - 32] = edges[r * 2 * EE + EE + e0 + (tid - 32)];
    else if (tid < 80) shInv[tid - 64] = inv_norm[r * 16 + (tid - 64)];
    __syncthreads();

    for (int e = 0; e < 32; e++) {
        int node = (tid < 128) ? shRow[e] : shCol[e];
        int kk = (tid < 128) ? tid : (tid - 128);
        shA[e * 276 + tid] = h[(size_t)node * 128 + kk];
    }
    if (tid < 32) {
        const int e = tid;
        const int ro = shRow[e], co = shCol[e];
        float cd[12];
#pragma unroll
        for (int i = 0; i < 12; i++) cd[i] = coord[(size_t)ro*12 + i] - coord[(size_t)co*12 + i];
#pragma unroll
        for (int i = 0; i < 12; i++) shCd[e * 12 + i] = cd[i];
#pragma unroll
        for (int c = 0; c < 4; c++)
#pragma unroll
            for (int d = 0; d < 4; d++) {
                float v = cd[c*3]*cd[d*3] + cd[c*3+1]*cd[d*3+1] + cd[c*3+2]*cd[d*3+2];
                shA[e * 276 + 256 + c * 4 + d] = v * shInv[c * 4 + d];
            }
        shA[e * 276 + 272] = eattr[r * EE + e0 + e];
        shA[e * 276 + 273] = 0.f; shA[e * 276 + 274] = 0.f; shA[e * 276 + 275] = 0.f;
    }
    __syncthreads();

    float acc[4][4];
    gemm_acc<DMSG, 276>(Wm1, shA, tid, acc);
    store_act(acc, bm1, shT, 132, tid, true);          // t1
    __syncthreads();
    gemm_acc<128, 132>(Wm2, shT, tid, acc);
    store_act(acc, bm2, shA, 132, tid, true);          // ef -> shA
    __syncthreads();
    gemm_acc<128, 132>(Wc1 + (size_t)r * 128 * 128, shA, tid, acc);
    store_act(acc, bc1 + r * 128, shT, 132, tid, true); // hid -> shT
    __syncthreads();

    // phi = hid @ Wc2[r]  (32 edges x 4)
    if (tid < 128) {
        const int e = tid >> 2, c = tid & 3;
        const float* w = Wc2 + (size_t)r * 512 + c;
        const float* trow = shT + e * 132;
        float p = 0.f;
        for (int k = 0; k < 128; k++) p = fmaf(trow[k], w[k * 4], p);
        shPhi[e * 4 + c] = p;
    }
    // per-edge agg contribution: ef @ Wrel[r]
    gemm_acc<128, 132>(Wrel + (size_t)r * 128 * 128, shA, tid, acc);
    __syncthreads();  // shPhi ready

    {
        const int tx = tid & 31, ty = tid >> 5;
#pragma unroll
        for (int ee = 0; ee < 4; ee++) {
            int row = shRow[ty * 4 + ee];
#pragma unroll
            for (int jj = 0; jj < 4; jj++)
                atomicAdd(&agg[(size_t)row * 128 + tx + 32 * jj], acc[ee][jj]);
        }
    }
    for (int idx = tid; idx < 32 * 12; idx += 256) {
        int e = idx / 12, q = idx - e * 12;
        atomicAdd(&sAccum[(size_t)shRow[e] * 12 + q], shCd[idx] * shPhi[e * 4 + q / 3]);
    }
    if (tid < 32) atomicAdd(&cnt[shRow[tid]], 1.0f);
}

// ---- kernel 3: node MLP + coordinate update ----
__global__ __launch_bounds__(256) void k_node(
    const float* __restrict__ h, const float* __restrict__ coord,
    const float* __restrict__ agg, const float* __restrict__ sAccum,
    const float* __restrict__ cnt,
    const float* __restrict__ Wn1, const float* __restrict__ bn1,
    const float* __restrict__ Wn2, const float* __restrict__ bn2,
    float* __restrict__ out)
{
    __shared__ __align__(16) float shA[32 * 260];
    __shared__ __align__(16) float shT[32 * 132];
    const int tid = threadIdx.x;
    const int n0 = blockIdx.x * 32;

    for (int e = 0; e < 32; e++) {
        int n = n0 + e;
        shA[e * 260 + tid] = (tid < 128) ? h[(size_t)n * 128 + tid]
                                         : agg[(size_t)n * 128 + (tid - 128)];
    }
    __syncthreads();
    float acc[4][4];
    gemm_acc<256, 260>(Wn1, shA, tid, acc);
    store_act(acc, bn1, shT, 132, tid, true);
    __syncthreads();
    gemm_acc<128, 132>(Wn2, shT, tid, acc);
    const int tx = tid & 31, ty = tid >> 5;
#pragma unroll
    for (int ee = 0; ee < 4; ee++) {
        int n = n0 + ty * 4 + ee;
#pragma unroll
        for (int jj = 0; jj < 4; jj++) {
            int j = tx + 32 * jj;
            out[(size_t)n * 128 + j] = h[(size_t)n * 128 + j] + acc[ee][jj] + bn2[j];
        }
    }
    for (int idx = tid; idx < 32 * 12; idx += 256) {
        int e = idx / 12, q = idx - e * 12;
        int n = n0 + e;
        out[OUT_X + (size_t)n * 12 + q] =
            coord[(size_t)n * 12 + q] + sAccum[(size_t)n * 12 + q] / fmaxf(cnt[n], 1.0f);
    }
}

// ---- kernel 4: edge output m ----
__global__ __launch_bounds__(256) void k_edge(
    const float* __restrict__ hnew, const float* __restrict__ eattr,
    const int* __restrict__ edges,
    const float* __restrict__ We1, const float* __restrict__ be1,
    const float* __restrict__ We2, const float* __restrict__ be2,
    float* __restrict__ mout)
{
    __shared__ __align__(16) float shA[32 * 260];
    __shared__ __align__(16) float shT[32 * 132];
    __shared__ int shRow[32], shCol[32];
    const int tid = threadIdx.x;
    const int r = blockIdx.y;
    const int e0 = blockIdx.x * 32;

    if (tid < 32) shRow[tid] = edges[r * 2 * EE + e0 + tid];
    else if (tid < 64) shCol[tid - 32] = edges[r * 2 * EE + EE + e0 + (tid - 32)];
    __syncthreads();

    for (int e = 0; e < 32; e++) {
        int row = shRow[e], col = shCol[e];
        for (int k = tid; k < 257; k += 256) {
            float v;
            if (k < 128) v = hnew[(size_t)row * 128 + k];
            else if (k == 128) v = eattr[r * EE + e0 + e];
            else v = hnew[(size_t)col * 128 + (k - 129)];
            shA[e * 260 + k] = v;
        }
    }
    __syncthreads();
    float acc[4][4];
    gemm_acc<257, 260>(We1, shA, tid, acc);
    store_act(acc, be1, shT, 132, tid, true);
    __syncthreads();

    const int e = tid >> 3, lane = tid & 7;
    const float* trow = shT + e * 132 + lane * 16;
    float p = 0.f;
#pragma unroll
    for (int k = 0; k < 16; k++) p = fmaf(trow[k], We2[lane * 16 + k], p);
    p += __shfl_down(p, 4, 8);
    p += __shfl_down(p, 2, 8);
    p += __shfl_down(p, 1, 8);
    if (lane == 0) mout[r * EE + e0 + e] = p + be2[0];
}

extern "C" void kernel_launch(void* const* d_in, const int* in_sizes, int n_in,
                              void* d_out, int out_size, void* d_ws, size_t ws_size,
                              hipStream_t stream)
{
    const float* h     = (const float*)d_in[0];
    const float* coord = (const float*)d_in[1];
    const float* eattr = (const float*)d_in[2];
    const int*   edges = (const int*)d_in[3];
    const float* Wm1 = (const float*)d_in[4];
    const float* bm1 = (const float*)d_in[5];
    const float* Wm2 = (const float*)d_in[6];
    const float* bm2 = (const float*)d_in[7];
    const float* We1 = (const float*)d_in[8];
    const float* be1 = (const float*)d_in[9];
    const float* We2 = (const float*)d_in[10];
    const float* be2 = (const float*)d_in[11];
    const float* Wn1 = (const float*)d_in[12];
    const float* bn1 = (const float*)d_in[13];
    const float* Wn2 = (const float*)d_in[14];
    const float* bn2 = (const float*)d_in[15];
    const float* Wrel = (const float*)d_in[16];
    const float* Wc1 = (const float*)d_in[17];
    const float* bc1 = (const float*)d_in[18];
    const float* Wc2 = (const float*)d_in[19];

    float* out = (float*)d_out;
    float* ws  = (float*)d_ws;

    float* nsq      = ws;            // 128
    float* inv_norm = ws + 128;      // 128
    float* cnt      = ws + 256;      // 20000
    float* sAccum   = ws + 20256;    // 240000
    float* agg      = ws + 260256;   // 2,560,000
    // total zeroed region: 2,820,256 floats
    hipMemsetAsync(d_ws, 0, (size_t)2820256 * sizeof(float), stream);

    k_norm<<<dim3(RR, 32), 256, 0, stream>>>(coord, edges, nsq);
    k_invnorm<<<1, 128, 0, stream>>>(nsq, inv_norm);
    k_msg<<<dim3(EE / 32, RR), 256, 0, stream>>>(h, coord, eattr, edges, inv_norm,
        Wm1, bm1, Wm2, bm2, Wc1, bc1, Wc2, Wrel, sAccum, cnt, agg);
    k_node<<<NN / 32, 256, 0, stream>>>(h, coord, agg, sAccum, cnt,
        Wn1, bn1, Wn2, bn2, out);
    k_edge<<<dim3(EE / 32, RR), 256, 0, stream>>>(out, eattr, edges,
        We1, be1, We2, be2, out + OUT_M);
}

// Round 2
// 472.454 us; speedup vs baseline: 2.9017x; 2.9017x over previous
//
#include <hip/hip_runtime.h>
#include <cmath>

#define NN 20000
#define FF 128
#define HH 128
#define EE 32768
#define RR 8

#define OUT_X (NN*FF)            // 2,560,000
#define OUT_M (NN*FF + NN*12)    // 2,800,000

typedef _Float16 half8 __attribute__((ext_vector_type(8)));
typedef float f32x4 __attribute__((ext_vector_type(4)));

#define MFMA16(a,b,c) __builtin_amdgcn_mfma_f32_16x16x32_f16(a, b, c, 0, 0, 0)

__device__ __forceinline__ float silu_f(float x) {
    return x / (1.0f + __expf(-x));
}
__device__ __forceinline__ unsigned short f2h(float x) {
    _Float16 h = (_Float16)x;
    return __builtin_bit_cast(unsigned short, h);
}
__device__ __forceinline__ float h2f(unsigned short u) {
    return (float)__builtin_bit_cast(_Float16, u);
}

// ============ MFMA tile GEMM: 32 rows x 128 cols, 256 threads ============
// sA: 32 x (CH*32) f16 in LDS, leading dim strideA elements (must be 8*odd).
// Bp: packed f16 weights, layout (((c*8+t)*4+q)*128 + n16*8 + j) == W[c*32+q*8+j][t*16+n16].
// Wave w computes m-tiles {0,1} x n-tiles {2w, 2w+1}. acc[m][i].
template<int CH>
__device__ __forceinline__ void mfma_gemm(const unsigned short* __restrict__ Bp,
                                          const unsigned short* sA, int strideA,
                                          int lane, int wid, f32x4 acc[2][2])
{
    const int n16 = lane & 15, q = lane >> 4;
#pragma unroll
    for (int m = 0; m < 2; m++)
#pragma unroll
        for (int i = 0; i < 2; i++) acc[m][i] = (f32x4)0.f;

    const unsigned short* a0p = sA + n16 * strideA;
    const unsigned short* a1p = sA + (16 + n16) * strideA;
#pragma unroll
    for (int c = 0; c < CH; c++) {
        const int ko = c * 32 + q * 8;
        half8 a0 = *(const half8*)(a0p + ko);
        half8 a1 = *(const half8*)(a1p + ko);
        const unsigned short* bb = Bp + (size_t)((c * 8 + 2 * wid) * 4 + q) * 128 + n16 * 8;
        half8 b0 = *(const half8*)(bb);
        half8 b1 = *(const half8*)(bb + 512);
        acc[0][0] = MFMA16(a0, b0, acc[0][0]);
        acc[0][1] = MFMA16(a0, b1, acc[0][1]);
        acc[1][0] = MFMA16(a1, b0, acc[1][0]);
        acc[1][1] = MFMA16(a1, b1, acc[1][1]);
    }
}

// C/D layout (verified): col = lane&15, row = (lane>>4)*4 + reg.
__device__ __forceinline__ void store_act(f32x4 acc[2][2], const float* __restrict__ bias,
                                          unsigned short* sOut, int strideOut,
                                          int lane, int wid, bool dosilu)
{
    const int n16 = lane & 15, q = lane >> 4;
#pragma unroll
    for (int i = 0; i < 2; i++) {
        const int n = (2 * wid + i) * 16 + n16;
        const float bb = bias[n];
#pragma unroll
        for (int m = 0; m < 2; m++) {
            const int rowb = m * 16 + q * 4;
#pragma unroll
            for (int r = 0; r < 4; r++) {
                float v = acc[m][i][r] + bb;
                if (dosilu) v = silu_f(v);
                sOut[(rowb + r) * strideOut + n] = f2h(v);
            }
        }
    }
}

// ============ prep kernels ============
__global__ __launch_bounds__(256) void k_cvt_h(const float* __restrict__ h,
                                               unsigned short* __restrict__ h_bf)
{
    const int i = (blockIdx.x * 256 + threadIdx.x) * 4;
    float4 v = *(const float4*)(h + i);
    unsigned short u[4] = { f2h(v.x), f2h(v.y), f2h(v.z), f2h(v.w) };
    *(uint2*)(h_bf + i) = *(const uint2*)u;
}

// pack W (batch x K x 128) into fragment order, C chunks of 32 (zero-padded)
__global__ __launch_bounds__(256) void k_pack(const float* __restrict__ W,
                                              unsigned short* __restrict__ dst, int K)
{
    const int p = blockIdx.x * 256 + threadIdx.x;
    const int per = gridDim.x * 256;
    const int batch = blockIdx.y;
    const float* Wb = W + (size_t)batch * K * 128;
    unsigned short* db = dst + (size_t)batch * per;
    const int j = p & 7, n16 = (p >> 3) & 15, q = (p >> 7) & 3, t = (p >> 9) & 7, c = p >> 12;
    const int k = c * 32 + q * 8 + j, n = t * 16 + n16;
    const float v = (k < K) ? Wb[(size_t)k * 128 + n] : 0.f;
    db[p] = f2h(v);
}

// ============ radial norm ============
__global__ __launch_bounds__(256) void k_norm(const float* __restrict__ coord,
                                              const int* __restrict__ edges,
                                              float* __restrict__ nsq)
{
    const int r = blockIdx.x;
    const int tid = threadIdx.x;
    const int* rows = edges + r * 2 * EE;
    const int* cols = rows + EE;
    float acc[16];
#pragma unroll
    for (int i = 0; i < 16; i++) acc[i] = 0.f;
    const int e0 = blockIdx.y * 1024;
    for (int e = e0 + tid; e < e0 + 1024; e += 256) {
        int ro = rows[e], co = cols[e];
        float cd[12];
        const float* cr = coord + (size_t)ro * 12;
        const float* cc = coord + (size_t)co * 12;
#pragma unroll
        for (int i = 0; i < 12; i++) cd[i] = cr[i] - cc[i];
#pragma unroll
        for (int c = 0; c < 4; c++)
#pragma unroll
            for (int d = 0; d < 4; d++) {
                float v = cd[c*3]*cd[d*3] + cd[c*3+1]*cd[d*3+1] + cd[c*3+2]*cd[d*3+2];
                acc[c*4+d] += v * v;
            }
    }
#pragma unroll
    for (int i = 0; i < 16; i++) {
        float v = acc[i];
        for (int off = 32; off; off >>= 1) v += __shfl_down(v, off, 64);
        if ((tid & 63) == 0) atomicAdd(&nsq[r * 16 + i], v);
    }
}

__global__ void k_invnorm(const float* __restrict__ nsq, float* __restrict__ inv_norm)
{
    int i = threadIdx.x;
    if (i < RR * 16) {
        float n = sqrtf(nsq[i]);
        inv_norm[i] = 1.0f / fmaxf(n, 1e-12f);
    }
}

// ============ message MLP + coord phi + scatters ============
__global__ __launch_bounds__(256) void k_msg(
    const unsigned short* __restrict__ h_bf, const float* __restrict__ coord,
    const float* __restrict__ eattr, const int* __restrict__ edges,
    const float* __restrict__ inv_norm,
    const unsigned short* __restrict__ Wm1p, const float* __restrict__ bm1,
    const unsigned short* __restrict__ Wm2p, const float* __restrict__ bm2,
    const unsigned short* __restrict__ Wc1p, const float* __restrict__ bc1,
    const float* __restrict__ Wc2, const unsigned short* __restrict__ Wrelp,
    float* __restrict__ sAccum, float* __restrict__ cnt, float* __restrict__ agg)
{
    __shared__ __align__(16) unsigned short shA[32 * 296]; // msg (stride 296); later ef (stride 136)
    __shared__ __align__(16) unsigned short shT[32 * 136]; // t1; later hid
    __shared__ float shCd[32 * 12];
    __shared__ float shPhi[32 * 4];
    __shared__ int shRow[32], shCol[32];
    __shared__ float shInv[16];

    const int tid = threadIdx.x;
    const int lane = tid & 63, wid = tid >> 6;
    const int r = blockIdx.y;
    const int e0 = blockIdx.x * 32;

    if (tid < 32) shRow[tid] = edges[r * 2 * EE + e0 + tid];
    else if (tid < 64) shCol[tid - 32] = edges[r * 2 * EE + EE + e0 + (tid - 32)];
    else if (tid < 80) shInv[tid - 64] = inv_norm[r * 16 + (tid - 64)];
    __syncthreads();

    // stage h[rows]|h[cols] (f16), 2 edges per pass
#pragma unroll 4
    for (int ee2 = 0; ee2 < 32; ee2 += 2) {
        const int e = ee2 + (tid >> 7);
        const int half = (tid >> 6) & 1;
        const int kk = (tid & 63) * 2;
        const int node = half ? shCol[e] : shRow[e];
        const unsigned v = *(const unsigned*)(h_bf + (size_t)node * 128 + kk);
        *(unsigned*)(shA + e * 296 + half * 128 + kk) = v;
    }
    if (tid < 32) {
        const int e = tid;
        const int ro = shRow[e], co = shCol[e];
        float cd[12];
#pragma unroll
        for (int i = 0; i < 12; i++) cd[i] = coord[(size_t)ro*12 + i] - coord[(size_t)co*12 + i];
#pragma unroll
        for (int i = 0; i < 12; i++) shCd[e * 12 + i] = cd[i];
#pragma unroll
        for (int c = 0; c < 4; c++)
#pragma unroll
            for (int d = 0; d < 4; d++) {
                float v = cd[c*3]*cd[d*3] + cd[c*3+1]*cd[d*3+1] + cd[c*3+2]*cd[d*3+2];
                shA[e * 296 + 256 + c * 4 + d] = f2h(v * shInv[c * 4 + d]);
            }
        shA[e * 296 + 272] = f2h(eattr[r * EE + e0 + e]);
#pragma unroll
        for (int k = 273; k < 288; k++) shA[e * 296 + k] = 0;
    }
    __syncthreads();

    f32x4 acc[2][2];
    mfma_gemm<9>(Wm1p, shA, 296, lane, wid, acc);          // msg @ Wm1
    store_act(acc, bm1, shT, 136, lane, wid, true);        // t1 -> shT
    __syncthreads();
    mfma_gemm<4>(Wm2p, shT, 136, lane, wid, acc);          // t1 @ Wm2
    store_act(acc, bm2, shA, 136, lane, wid, true);        // ef -> shA (reuse)
    __syncthreads();
    mfma_gemm<4>(Wc1p + (size_t)r * 16384, shA, 136, lane, wid, acc);
    store_act(acc, bc1 + r * 128, shT, 136, lane, wid, true); // hid -> shT
    __syncthreads();

    // agg contribution: ef @ Wrel[r] -> atomics (no bias)
    mfma_gemm<4>(Wrelp + (size_t)r * 16384, shA, 136, lane, wid, acc);
    {
        const int n16 = lane & 15, q = lane >> 4;
#pragma unroll
        for (int i = 0; i < 2; i++) {
            const int n = (2 * wid + i) * 16 + n16;
#pragma unroll
            for (int m = 0; m < 2; m++) {
                const int rowb = m * 16 + q * 4;
#pragma unroll
                for (int rr = 0; rr < 4; rr++)
                    atomicAdd(&agg[(size_t)shRow[rowb + rr] * 128 + n], acc[m][i][rr]);
            }
        }
    }

    // phi = hid @ Wc2[r]   (32 x 4)
    if (tid < 128) {
        const int e = tid >> 2, c = tid & 3;
        const float* w = Wc2 + (size_t)r * 512 + c;
        const unsigned short* trow = shT + e * 136;
        float p = 0.f;
        for (int k = 0; k < 128; k++) p = fmaf(h2f(trow[k]), w[k * 4], p);
        shPhi[e * 4 + c] = p;
    }
    __syncthreads();

    for (int idx = tid; idx < 32 * 12; idx += 256) {
        const int e = idx / 12, qq = idx - e * 12;
        atomicAdd(&sAccum[(size_t)shRow[e] * 12 + qq], shCd[idx] * shPhi[e * 4 + qq / 3]);
    }
    if (tid < 32) atomicAdd(&cnt[shRow[tid]], 1.0f);
}

// ============ node MLP + coordinate update ============
__global__ __launch_bounds__(256) void k_node(
    const float* __restrict__ h, const unsigned short* __restrict__ h_bf,
    const float* __restrict__ coord,
    const float* __restrict__ agg, const float* __restrict__ sAccum,
    const float* __restrict__ cnt,
    const unsigned short* __restrict__ Wn1p, const float* __restrict__ bn1,
    const unsigned short* __restrict__ Wn2p, const float* __restrict__ bn2,
    float* __restrict__ out, unsigned short* __restrict__ hnew_bf)
{
    __shared__ __align__(16) unsigned short shA[32 * 264];
    __shared__ __align__(16) unsigned short shT[32 * 136];
    const int tid = threadIdx.x;
    const int lane = tid & 63, wid = tid >> 6;
    const int n0 = blockIdx.x * 32;

    for (int e = 0; e < 32; e++) {
        const int n = n0 + e;
        if (tid < 128) shA[e * 264 + tid] = h_bf[(size_t)n * 128 + tid];
        else shA[e * 264 + 128 + (tid - 128)] = f2h(agg[(size_t)n * 128 + (tid - 128)]);
    }
    __syncthreads();
    f32x4 acc[2][2];
    mfma_gemm<8>(Wn1p, shA, 264, lane, wid, acc);
    store_act(acc, bn1, shT, 136, lane, wid, true);
    __syncthreads();
    mfma_gemm<4>(Wn2p, shT, 136, lane, wid, acc);
    {
        const int n16 = lane & 15, q = lane >> 4;
#pragma unroll
        for (int i = 0; i < 2; i++) {
            const int n = (2 * wid + i) * 16 + n16;
            const float bb = bn2[n];
#pragma unroll
            for (int m = 0; m < 2; m++) {
                const int rowb = m * 16 + q * 4;
#pragma unroll
                for (int rr = 0; rr < 4; rr++) {
                    const int node = n0 + rowb + rr;
                    const float v = h[(size_t)node * 128 + n] + acc[m][i][rr] + bb;
                    out[(size_t)node * 128 + n] = v;
                    hnew_bf[(size_t)node * 128 + n] = f2h(v);
                }
            }
        }
    }
    for (int idx = tid; idx < 32 * 12; idx += 256) {
        const int e = idx / 12, qq = idx - e * 12;
        const int n = n0 + e;
        out[OUT_X + (size_t)n * 12 + qq] =
            coord[(size_t)n * 12 + qq] + sAccum[(size_t)n * 12 + qq] / fmaxf(cnt[n], 1.0f);
    }
}

// ============ edge output m ============
__global__ __launch_bounds__(256) void k_edge(
    const unsigned short* __restrict__ hnew_bf, const float* __restrict__ eattr,
    const int* __restrict__ edges,
    const unsigned short* __restrict__ We1p, const float* __restrict__ be1,
    const float* __restrict__ We2, const float* __restrict__ be2,
    float* __restrict__ mout)
{
    __shared__ __align__(16) unsigned short shA[32 * 296];
    __shared__ __align__(16) unsigned short shT[32 * 136];
    __shared__ int shRow[32], shCol[32];
    const int tid = threadIdx.x;
    const int lane = tid & 63, wid = tid >> 6;
    const int r = blockIdx.y;
    const int e0 = blockIdx.x * 32;

    if (tid < 32) shRow[tid] = edges[r * 2 * EE + e0 + tid];
    else if (tid < 64) shCol[tid - 32] = edges[r * 2 * EE + EE + e0 + (tid - 32)];
    __syncthreads();

    for (int e = 0; e < 32; e++) {
        if (tid < 128) shA[e * 296 + tid] = hnew_bf[(size_t)shRow[e] * 128 + tid];
        else shA[e * 296 + 129 + (tid - 128)] = hnew_bf[(size_t)shCol[e] * 128 + (tid - 128)];
    }
    if (tid < 32) {
        const int e = tid;
        shA[e * 296 + 128] = f2h(eattr[r * EE + e0 + e]);
#pragma unroll
        for (int k = 257; k < 288; k++) shA[e * 296 + k] = 0;
    }
    __syncthreads();
    f32x4 acc[2][2];
    mfma_gemm<9>(We1p, shA, 296, lane, wid, acc);
    store_act(acc, be1, shT, 136, lane, wid, true);
    __syncthreads();

    const int e = tid >> 3, l8 = tid & 7;
    const unsigned short* trow = shT + e * 136 + l8 * 16;
    float p = 0.f;
#pragma unroll
    for (int k = 0; k < 16; k++) p = fmaf(h2f(trow[k]), We2[l8 * 16 + k], p);
    p += __shfl_down(p, 4, 8);
    p += __shfl_down(p, 2, 8);
    p += __shfl_down(p, 1, 8);
    if (l8 == 0) mout[r * EE + e0 + e] = p + be2[0];
}

extern "C" void kernel_launch(void* const* d_in, const int* in_sizes, int n_in,
                              void* d_out, int out_size, void* d_ws, size_t ws_size,
                              hipStream_t stream)
{
    const float* h     = (const float*)d_in[0];
    const float* coord = (const float*)d_in[1];
    const float* eattr = (const float*)d_in[2];
    const int*   edges = (const int*)d_in[3];
    const float* Wm1 = (const float*)d_in[4];
    const float* bm1 = (const float*)d_in[5];
    const float* Wm2 = (const float*)d_in[6];
    const float* bm2 = (const float*)d_in[7];
    const float* We1 = (const float*)d_in[8];
    const float* be1 = (const float*)d_in[9];
    const float* We2 = (const float*)d_in[10];
    const float* be2 = (const float*)d_in[11];
    const float* Wn1 = (const float*)d_in[12];
    const float* bn1 = (const float*)d_in[13];
    const float* Wn2 = (const float*)d_in[14];
    const float* bn2 = (const float*)d_in[15];
    const float* Wrel = (const float*)d_in[16];
    const float* Wc1 = (const float*)d_in[17];
    const float* bc1 = (const float*)d_in[18];
    const float* Wc2 = (const float*)d_in[19];

    float* out = (float*)d_out;
    float* ws  = (float*)d_ws;

    float* nsq      = ws;            // 128
    float* inv_norm = ws + 128;      // 128
    float* cnt      = ws + 256;      // 20000
    float* sAccum   = ws + 20256;    // 240000
    float* agg      = ws + 260256;   // 2,560,000
    // zeroed region: 2,820,256 floats
    unsigned short* U = (unsigned short*)(ws + 2820256);
    unsigned short* h_bf    = U;                 // 2,560,000
    unsigned short* hnew_bf = U + 2560000;       // 2,560,000
    unsigned short* Wm1p    = U + 5120000;       // 9*4096 = 36864
    unsigned short* Wm2p    = U + 5156864;       // 16384
    unsigned short* Wn1p    = U + 5173248;       // 32768
    unsigned short* Wn2p    = U + 5206016;       // 16384
    unsigned short* We1p    = U + 5222400;       // 36864
    unsigned short* Wc1p    = U + 5259264;       // 8*16384 = 131072
    unsigned short* Wrelp   = U + 5390336;       // 8*16384 = 131072
    // total ws use ~22.3 MB

    hipMemsetAsync(d_ws, 0, (size_t)2820256 * sizeof(float), stream);

    k_cvt_h<<<2500, 256, 0, stream>>>(h, h_bf);
    k_pack<<<dim3(144, 1), 256, 0, stream>>>(Wm1, Wm1p, 273);
    k_pack<<<dim3(64, 1),  256, 0, stream>>>(Wm2, Wm2p, 128);
    k_pack<<<dim3(128, 1), 256, 0, stream>>>(Wn1, Wn1p, 256);
    k_pack<<<dim3(64, 1),  256, 0, stream>>>(Wn2, Wn2p, 128);
    k_pack<<<dim3(144, 1), 256, 0, stream>>>(We1, We1p, 257);
    k_pack<<<dim3(64, 8),  256, 0, stream>>>(Wc1, Wc1p, 128);
    k_pack<<<dim3(64, 8),  256, 0, stream>>>(Wrel, Wrelp, 128);

    k_norm<<<dim3(RR, 32), 256, 0, stream>>>(coord, edges, nsq);
    k_invnorm<<<1, 128, 0, stream>>>(nsq, inv_norm);
    k_msg<<<dim3(EE / 32, RR), 256, 0, stream>>>(h_bf, coord, eattr, edges, inv_norm,
        Wm1p, bm1, Wm2p, bm2, Wc1p, bc1, Wc2, Wrelp, sAccum, cnt, agg);
    k_node<<<NN / 32, 256, 0, stream>>>(h, h_bf, coord, agg, sAccum, cnt,
        Wn1p, bn1, Wn2p, bn2, out, hnew_bf);
    k_edge<<<dim3(EE / 32, RR), 256, 0, stream>>>(hnew_bf, eattr, edges,
        We1p, be1, We2, be2, out + OUT_M);
}

// Round 3
// 455.127 us; speedup vs baseline: 3.0122x; 1.0381x over previous
//
#include <hip/hip_runtime.h>
#include <hip/hip_fp16.h>
#include <cmath>

#define NN 20000
#define FF 128
#define EE 32768
#define RR 8

#define OUT_X (NN*FF)            // 2,560,000
#define OUT_M (NN*FF + NN*12)    // 2,800,000

typedef _Float16 half8 __attribute__((ext_vector_type(8)));
typedef float f32x4 __attribute__((ext_vector_type(4)));

#define MFMA16(a,b,c) __builtin_amdgcn_mfma_f32_16x16x32_f16(a, b, c, 0, 0, 0)

__device__ __forceinline__ float silu_f(float x) {
    return x / (1.0f + __expf(-x));
}
__device__ __forceinline__ unsigned short f2h(float x) {
    _Float16 h = (_Float16)x;
    return __builtin_bit_cast(unsigned short, h);
}
__device__ __forceinline__ float h2f(unsigned short u) {
    return (float)__builtin_bit_cast(_Float16, u);
}

__device__ __forceinline__ void seg_atomic(unsigned short* p, unsigned bits) {
#if __has_builtin(__builtin_amdgcn_flat_atomic_fadd_v2f16)
    typedef _Float16 v2h __attribute__((ext_vector_type(2)));
    v2h v = __builtin_bit_cast(v2h, bits);
    __builtin_amdgcn_flat_atomic_fadd_v2f16((v2h*)p, v);
#else
    __half2 v = __builtin_bit_cast(__half2, bits);
    unsafeAtomicAdd((__half2*)p, v);
#endif
}

__device__ __forceinline__ void zero4(f32x4 acc[4][2]) {
#pragma unroll
    for (int m = 0; m < 4; m++) { acc[m][0] = (f32x4)0.f; acc[m][1] = (f32x4)0.f; }
}

// one K-chunk (32) against 2 n-tiles (per wave), 4 m-tiles
__device__ __forceinline__ void mfma_chunk(const unsigned short* __restrict__ Bp, int c,
                                           int wid, int q, int n16,
                                           const half8 a[4], f32x4 acc[4][2])
{
    const unsigned short* bb = Bp + (size_t)(((c * 8 + 2 * wid) * 4) + q) * 128 + n16 * 8;
    half8 b0 = *(const half8*)bb;
    half8 b1 = *(const half8*)(bb + 512);
#pragma unroll
    for (int m = 0; m < 4; m++) {
        acc[m][0] = MFMA16(a[m], b0, acc[m][0]);
        acc[m][1] = MFMA16(a[m], b1, acc[m][1]);
    }
}

// A from LDS tile (64 x NCH*32, stride 136)
template<int NCH>
__device__ __forceinline__ void gemm_lds(const unsigned short* __restrict__ Bp,
                                         const unsigned short* sA,
                                         int wid, int q, int n16, f32x4 acc[4][2])
{
#pragma unroll
    for (int c = 0; c < NCH; c++) {
        half8 a[4];
#pragma unroll
        for (int m = 0; m < 4; m++)
            a[m] = *(const half8*)(sA + (m * 16 + n16) * 136 + c * 32 + q * 8);
        mfma_chunk(Bp, c, wid, q, n16, a, acc);
    }
}

// C/D layout: col = lane&15, row = (lane>>4)*4 + reg
__device__ __forceinline__ void store_act4(f32x4 acc[4][2], const float* __restrict__ bias,
                                           unsigned short* sOut, int n16, int q, int wid, bool dosilu)
{
#pragma unroll
    for (int i = 0; i < 2; i++) {
        const int n = (2 * wid + i) * 16 + n16;
        const float bb = bias[n];
#pragma unroll
        for (int m = 0; m < 4; m++)
#pragma unroll
            for (int rr = 0; rr < 4; rr++) {
                float v = acc[m][i][rr] + bb;
                if (dosilu) v = silu_f(v);
                sOut[(m * 16 + q * 4 + rr) * 136 + n] = f2h(v);
            }
    }
}
__device__ __forceinline__ void store_raw4(f32x4 acc[4][2], unsigned short* sOut,
                                           int n16, int q, int wid)
{
#pragma unroll
    for (int i = 0; i < 2; i++) {
        const int n = (2 * wid + i) * 16 + n16;
#pragma unroll
        for (int m = 0; m < 4; m++)
#pragma unroll
            for (int rr = 0; rr < 4; rr++)
                sOut[(m * 16 + q * 4 + rr) * 136 + n] = f2h(acc[m][i][rr]);
    }
}

// ============ prep ============
__global__ __launch_bounds__(256) void k_cvt_h(const float* __restrict__ h,
                                               unsigned short* __restrict__ h_bf)
{
    const int i = (blockIdx.x * 256 + threadIdx.x) * 4;
    float4 v = *(const float4*)(h + i);
    unsigned short u[4] = { f2h(v.x), f2h(v.y), f2h(v.z), f2h(v.w) };
    *(uint2*)(h_bf + i) = *(const uint2*)u;
}

// pack W (batch x K x 128) to fragment order; remap=1 permutes K for We1:
// dst-K order = [rows(0..127) | cols(src 129..256) | eattr(src 128) | pad]
__global__ __launch_bounds__(256) void k_pack(const float* __restrict__ W,
                                              unsigned short* __restrict__ dst,
                                              int K, int remap)
{
    const int p = blockIdx.x * 256 + threadIdx.x;
    const int per = gridDim.x * 256;
    const int batch = blockIdx.y;
    const float* Wb = W + (size_t)batch * K * 128;
    unsigned short* db = dst + (size_t)batch * per;
    const int j = p & 7, n16 = (p >> 3) & 15, q = (p >> 7) & 3, t = (p >> 9) & 7, c = p >> 12;
    int k = c * 32 + q * 8 + j;
    if (remap) k = (k < 128) ? k : (k < 256) ? (k + 1) : (k == 256 ? 128 : K);
    const int n = t * 16 + n16;
    const float v = (k < K) ? Wb[(size_t)k * 128 + n] : 0.f;
    db[p] = f2h(v);
}

// Wc2 (R x 128 x 4) -> single n-tile pack, pre-scaled by 256
__global__ __launch_bounds__(256) void k_pack_wc2(const float* __restrict__ Wc2,
                                                  unsigned short* __restrict__ dst)
{
    const int p = blockIdx.x * 256 + threadIdx.x;   // 0..2047
    const int r = blockIdx.y;
    const int j = p & 7, n16 = (p >> 3) & 15, q = (p >> 7) & 3, c = (p >> 9) & 3;
    const int k = c * 32 + q * 8 + j;
    float v = (n16 < 4) ? Wc2[(size_t)r * 512 + k * 4 + n16] * 256.0f : 0.f;
    dst[(size_t)r * 2048 + p] = f2h(v);
}

// ============ radial norm ============
__global__ __launch_bounds__(256) void k_norm(const float* __restrict__ coord,
                                              const int* __restrict__ edges,
                                              float* __restrict__ nsq)
{
    const int r = blockIdx.x;
    const int tid = threadIdx.x;
    const int* rows = edges + r * 2 * EE;
    const int* cols = rows + EE;
    float acc[16];
#pragma unroll
    for (int i = 0; i < 16; i++) acc[i] = 0.f;
    const int e0 = blockIdx.y * 1024;
    for (int e = e0 + tid; e < e0 + 1024; e += 256) {
        const float4* cr = (const float4*)(coord + (size_t)rows[e] * 12);
        const float4* cc = (const float4*)(coord + (size_t)cols[e] * 12);
        float4 a0 = cr[0], a1 = cr[1], a2 = cr[2];
        float4 b0 = cc[0], b1 = cc[1], b2 = cc[2];
        float cd[12] = { a0.x-b0.x, a0.y-b0.y, a0.z-b0.z, a0.w-b0.w,
                         a1.x-b1.x, a1.y-b1.y, a1.z-b1.z, a1.w-b1.w,
                         a2.x-b2.x, a2.y-b2.y, a2.z-b2.z, a2.w-b2.w };
#pragma unroll
        for (int c = 0; c < 4; c++)
#pragma unroll
            for (int d = 0; d < 4; d++) {
                float v = cd[c*3]*cd[d*3] + cd[c*3+1]*cd[d*3+1] + cd[c*3+2]*cd[d*3+2];
                acc[c*4+d] += v * v;
            }
    }
#pragma unroll
    for (int i = 0; i < 16; i++) {
        float v = acc[i];
        for (int off = 32; off; off >>= 1) v += __shfl_down(v, off, 64);
        if ((tid & 63) == 0) atomicAdd(&nsq[r * 16 + i], v);
    }
}

__global__ void k_invnorm(const float* __restrict__ nsq, float* __restrict__ inv_norm)
{
    int i = threadIdx.x;
    if (i < RR * 16) {
        float n = sqrtf(nsq[i]);
        inv_norm[i] = 1.0f / fmaxf(n, 1e-12f);
    }
}

// ============ message MLP + phi + scatters (64 edges/block) ============
__global__ __launch_bounds__(256, 2) void k_msg(
    const unsigned short* __restrict__ h_bf, const float* __restrict__ coord,
    const float* __restrict__ eattr, const int* __restrict__ edges,
    const float* __restrict__ inv_norm,
    const unsigned short* __restrict__ Wm1p, const float* __restrict__ bm1,
    const unsigned short* __restrict__ Wm2p, const float* __restrict__ bm2,
    const unsigned short* __restrict__ Wc1p, const float* __restrict__ bc1,
    const unsigned short* __restrict__ Wc2p,
    float* __restrict__ sAccum, float* __restrict__ cnt,
    unsigned short* __restrict__ seg)
{
    __shared__ __align__(16) unsigned short shX[64 * 40];   // radial|eattr (K 256..287)
    __shared__ __align__(16) unsigned short shT[64 * 136];  // t1, then hid
    __shared__ __align__(16) unsigned short shE[64 * 136];  // ef
    __shared__ float shCd[64 * 12];
    __shared__ float shPhi[64 * 4];
    __shared__ int shRow[64], shCol[64];
    __shared__ float shInv[16];

    const int tid = threadIdx.x;
    const int lane = tid & 63, wid = tid >> 6;
    const int n16 = lane & 15, q = lane >> 4;
    const int r = blockIdx.y;
    const int e0 = blockIdx.x * 64;
    const int ko = q * 8;

    if (tid < 64) shRow[tid] = edges[r * 2 * EE + e0 + tid];
    else if (tid < 128) shCol[tid - 64] = edges[r * 2 * EE + EE + e0 + (tid - 64)];
    else if (tid < 144) shInv[tid - 128] = inv_norm[r * 16 + (tid - 128)];
    __syncthreads();

    if (tid < 64) {
        const int e = tid;
        const float4* cr = (const float4*)(coord + (size_t)shRow[e] * 12);
        const float4* cc = (const float4*)(coord + (size_t)shCol[e] * 12);
        float4 a0 = cr[0], a1 = cr[1], a2 = cr[2];
        float4 b0 = cc[0], b1 = cc[1], b2 = cc[2];
        float cd[12] = { a0.x-b0.x, a0.y-b0.y, a0.z-b0.z, a0.w-b0.w,
                         a1.x-b1.x, a1.y-b1.y, a1.z-b1.z, a1.w-b1.w,
                         a2.x-b2.x, a2.y-b2.y, a2.z-b2.z, a2.w-b2.w };
#pragma unroll
        for (int i2 = 0; i2 < 12; i2++) shCd[e * 12 + i2] = cd[i2];
#pragma unroll
        for (int c = 0; c < 4; c++)
#pragma unroll
            for (int d = 0; d < 4; d++) {
                float v = cd[c*3]*cd[d*3] + cd[c*3+1]*cd[d*3+1] + cd[c*3+2]*cd[d*3+2];
                shX[e * 40 + c * 4 + d] = f2h(v * shInv[c * 4 + d]);
            }
        shX[e * 40 + 16] = f2h(eattr[(size_t)r * EE + e0 + e]);
#pragma unroll
        for (int k2 = 17; k2 < 32; k2++) shX[e * 40 + k2] = 0;
    }
    const unsigned short* rowP[4];
    const unsigned short* colP[4];
#pragma unroll
    for (int m = 0; m < 4; m++) {
        rowP[m] = h_bf + (size_t)shRow[m * 16 + n16] * 128;
        colP[m] = h_bf + (size_t)shCol[m * 16 + n16] * 128;
    }
    __syncthreads();

    f32x4 acc[4][2];
    zero4(acc);
#pragma unroll
    for (int c = 0; c < 4; c++) {
        half8 a[4];
#pragma unroll
        for (int m = 0; m < 4; m++) a[m] = *(const half8*)(rowP[m] + c * 32 + ko);
        mfma_chunk(Wm1p, c, wid, q, n16, a, acc);
    }
#pragma unroll
    for (int c = 0; c < 4; c++) {
        half8 a[4];
#pragma unroll
        for (int m = 0; m < 4; m++) a[m] = *(const half8*)(colP[m] + c * 32 + ko);
        mfma_chunk(Wm1p, c + 4, wid, q, n16, a, acc);
    }
    {
        half8 a[4];
#pragma unroll
        for (int m = 0; m < 4; m++) a[m] = *(const half8*)(shX + (m * 16 + n16) * 40 + ko);
        mfma_chunk(Wm1p, 8, wid, q, n16, a, acc);
    }
    store_act4(acc, bm1, shT, n16, q, wid, true);     // t1
    __syncthreads();

    zero4(acc);
    gemm_lds<4>(Wm2p, shT, wid, q, n16, acc);
    store_act4(acc, bm2, shE, n16, q, wid, true);     // ef
    __syncthreads();

    zero4(acc);
    gemm_lds<4>(Wc1p + (size_t)r * 16384, shE, wid, q, n16, acc);
    store_act4(acc, bc1 + r * 128, shT, n16, q, wid, true);  // hid

    // seg += ef (packed f16 atomics, pairs read as dwords from LDS)
    {
        unsigned short* segr = seg + (size_t)r * NN * 128;
        for (int it = tid; it < 64 * 64; it += 256) {
            const int e = it >> 6, jj = it & 63;
            const unsigned bits = *(const unsigned*)(shE + e * 136 + jj * 2);
            seg_atomic(segr + (size_t)shRow[e] * 128 + jj * 2, bits);
        }
    }
    __syncthreads();

    // phi = hid @ Wc2p[r] / 256  (wave handles m-tile = wid)
    {
        f32x4 ap = (f32x4)0.f;
        const unsigned short* Bw = Wc2p + (size_t)r * 2048;
#pragma unroll
        for (int c = 0; c < 4; c++) {
            half8 a = *(const half8*)(shT + (wid * 16 + n16) * 136 + c * 32 + ko);
            half8 b = *(const half8*)(Bw + (c * 4 + q) * 128 + n16 * 8);
            ap = MFMA16(a, b, ap);
        }
        if (n16 < 4) {
#pragma unroll
            for (int rr = 0; rr < 4; rr++)
                shPhi[(wid * 16 + q * 4 + rr) * 4 + n16] = ap[rr] * (1.0f / 256.0f);
        }
    }
    __syncthreads();

    for (int it = tid; it < 1024; it += 256) {
        const int e = it >> 4, s = it & 15;
        if (s < 12) {
            const int c = (s * 86) >> 8;   // s/3
            const float v = shCd[e * 12 + s] * shPhi[e * 4 + c];
            atomicAdd(&sAccum[(size_t)shRow[e] * 12 + s], v);
        }
    }
    if (tid < 64) atomicAdd(&cnt[shRow[tid]], 1.0f);
}

// ============ node: agg GEMM (seg@Wrel) + node MLP + coord (64 nodes/block) ============
__global__ __launch_bounds__(256, 2) void k_node(
    const float* __restrict__ h, const unsigned short* __restrict__ h_bf,
    const float* __restrict__ coord,
    const unsigned short* __restrict__ seg, const float* __restrict__ sAccum,
    const float* __restrict__ cnt,
    const unsigned short* __restrict__ Wrelp,
    const unsigned short* __restrict__ Wn1p, const float* __restrict__ bn1,
    const unsigned short* __restrict__ Wn2p, const float* __restrict__ bn2,
    float* __restrict__ out, unsigned short* __restrict__ hnew_bf)
{
    __shared__ __align__(16) unsigned short shAgg[64 * 136];
    __shared__ __align__(16) unsigned short shT[64 * 136];
    const int tid = threadIdx.x;
    const int lane = tid & 63, wid = tid >> 6;
    const int n16 = lane & 15, q = lane >> 4;
    const int n0 = blockIdx.x * 64;
    const int ko = q * 8;

    int nodeA[4];
#pragma unroll
    for (int m = 0; m < 4; m++) nodeA[m] = min(n0 + m * 16 + n16, NN - 1);

    f32x4 acc[4][2];
    zero4(acc);
#pragma unroll
    for (int r = 0; r < RR; r++) {
        const unsigned short* segr = seg + (size_t)r * NN * 128;
        const unsigned short* Bp = Wrelp + (size_t)r * 16384;
#pragma unroll
        for (int c = 0; c < 4; c++) {
            half8 a[4];
#pragma unroll
            for (int m = 0; m < 4; m++)
                a[m] = *(const half8*)(segr + (size_t)nodeA[m] * 128 + c * 32 + ko);
            mfma_chunk(Bp, c, wid, q, n16, a, acc);
        }
    }
    store_raw4(acc, shAgg, n16, q, wid);
    __syncthreads();

    zero4(acc);
#pragma unroll
    for (int c = 0; c < 4; c++) {
        half8 a[4];
#pragma unroll
        for (int m = 0; m < 4; m++)
            a[m] = *(const half8*)(h_bf + (size_t)nodeA[m] * 128 + c * 32 + ko);
        mfma_chunk(Wn1p, c, wid, q, n16, a, acc);
    }
#pragma unroll
    for (int c = 4; c < 8; c++) {
        half8 a[4];
#pragma unroll
        for (int m = 0; m < 4; m++)
            a[m] = *(const half8*)(shAgg + (m * 16 + n16) * 136 + (c - 4) * 32 + ko);
        mfma_chunk(Wn1p, c, wid, q, n16, a, acc);
    }
    store_act4(acc, bn1, shT, n16, q, wid, true);
    __syncthreads();

    zero4(acc);
    gemm_lds<4>(Wn2p, shT, wid, q, n16, acc);
#pragma unroll
    for (int i = 0; i < 2; i++) {
        const int n = (2 * wid + i) * 16 + n16;
        const float bb = bn2[n];
#pragma unroll
        for (int m = 0; m < 4; m++)
#pragma unroll
            for (int rr = 0; rr < 4; rr++) {
                const int node = n0 + m * 16 + q * 4 + rr;
                if (node < NN) {
                    const float v = h[(size_t)node * 128 + n] + acc[m][i][rr] + bb;
                    out[(size_t)node * 128 + n] = v;
                    hnew_bf[(size_t)node * 128 + n] = f2h(v);
                }
            }
    }
    if (tid < 64) {
        const int node = n0 + tid;
        if (node < NN) {
            const float ic = 1.0f / fmaxf(cnt[node], 1.0f);
#pragma unroll
            for (int j2 = 0; j2 < 12; j2++)
                out[OUT_X + (size_t)node * 12 + j2] =
                    coord[(size_t)node * 12 + j2] + sAccum[(size_t)node * 12 + j2] * ic;
        }
    }
}

// ============ edge output m (64 edges/block) ============
__global__ __launch_bounds__(256, 2) void k_edge(
    const unsigned short* __restrict__ hnew_bf, const float* __restrict__ eattr,
    const int* __restrict__ edges,
    const unsigned short* __restrict__ We1p, const float* __restrict__ be1,
    const float* __restrict__ We2, const float* __restrict__ be2,
    float* __restrict__ mout)
{
    __shared__ __align__(16) unsigned short shX[64 * 40];
    __shared__ __align__(16) unsigned short shT[64 * 136];
    __shared__ float shW[128];
    __shared__ int shRow[64], shCol[64];
    const int tid = threadIdx.x;
    const int lane = tid & 63, wid = tid >> 6;
    const int n16 = lane & 15, q = lane >> 4;
    const int r = blockIdx.y;
    const int e0 = blockIdx.x * 64;
    const int ko = q * 8;

    if (tid < 64) shRow[tid] = edges[r * 2 * EE + e0 + tid];
    else if (tid < 128) shCol[tid - 64] = edges[r * 2 * EE + EE + e0 + (tid - 64)];
    else shW[tid - 128] = We2[tid - 128];
    __syncthreads();

    if (tid < 64) {
        shX[tid * 40] = f2h(eattr[(size_t)r * EE + e0 + tid]);
#pragma unroll
        for (int k2 = 1; k2 < 32; k2++) shX[tid * 40 + k2] = 0;
    }
    const unsigned short* rowP[4];
    const unsigned short* colP[4];
#pragma unroll
    for (int m = 0; m < 4; m++) {
        rowP[m] = hnew_bf + (size_t)shRow[m * 16 + n16] * 128;
        colP[m] = hnew_bf + (size_t)shCol[m * 16 + n16] * 128;
    }
    __syncthreads();

    f32x4 acc[4][2];
    zero4(acc);
#pragma unroll
    for (int c = 0; c < 4; c++) {
        half8 a[4];
#pragma unroll
        for (int m = 0; m < 4; m++) a[m] = *(const half8*)(rowP[m] + c * 32 + ko);
        mfma_chunk(We1p, c, wid, q, n16, a, acc);
    }
#pragma unroll
    for (int c = 0; c < 4; c++) {
        half8 a[4];
#pragma unroll
        for (int m = 0; m < 4; m++) a[m] = *(const half8*)(colP[m] + c * 32 + ko);
        mfma_chunk(We1p, c + 4, wid, q, n16, a, acc);
    }
    {
        half8 a[4];
#pragma unroll
        for (int m = 0; m < 4; m++) a[m] = *(const half8*)(shX + (m * 16 + n16) * 40 + ko);
        mfma_chunk(We1p, 8, wid, q, n16, a, acc);
    }
    store_act4(acc, be1, shT, n16, q, wid, true);
    __syncthreads();

    const int e = tid >> 2, qq = tid & 3;
    const unsigned short* trow = shT + e * 136 + qq * 32;
    float p = 0.f;
#pragma unroll
    for (int k = 0; k < 32; k++) p = fmaf(h2f(trow[k]), shW[qq * 32 + k], p);
    p += __shfl_down(p, 2, 4);
    p += __shfl_down(p, 1, 4);
    if (qq == 0) mout[(size_t)r * EE + e0 + e] = p + be2[0];
}

extern "C" void kernel_launch(void* const* d_in, const int* in_sizes, int n_in,
                              void* d_out, int out_size, void* d_ws, size_t ws_size,
                              hipStream_t stream)
{
    const float* h     = (const float*)d_in[0];
    const float* coord = (const float*)d_in[1];
    const float* eattr = (const float*)d_in[2];
    const int*   edges = (const int*)d_in[3];
    const float* Wm1 = (const float*)d_in[4];
    const float* bm1 = (const float*)d_in[5];
    const float* Wm2 = (const float*)d_in[6];
    const float* bm2 = (const float*)d_in[7];
    const float* We1 = (const float*)d_in[8];
    const float* be1 = (const float*)d_in[9];
    const float* We2 = (const float*)d_in[10];
    const float* be2 = (const float*)d_in[11];
    const float* Wn1 = (const float*)d_in[12];
    const float* bn1 = (const float*)d_in[13];
    const float* Wn2 = (const float*)d_in[14];
    const float* bn2 = (const float*)d_in[15];
    const float* Wrel = (const float*)d_in[16];
    const float* Wc1 = (const float*)d_in[17];
    const float* bc1 = (const float*)d_in[18];
    const float* Wc2 = (const float*)d_in[19];

    float* out = (float*)d_out;
    float* ws  = (float*)d_ws;

    float* nsq      = ws;            // 128
    float* inv_norm = ws + 128;      // 128
    float* cnt      = ws + 256;      // 20000
    float* sAccum   = ws + 20256;    // 240000  -> zero region ends at 260256 f32
    unsigned short* U = (unsigned short*)(ws + 260256);
    unsigned short* seg     = U;                   // 8*20000*128 = 20,480,000 (zeroed)
    unsigned short* h_bf    = U + 20480000;        // 2,560,000
    unsigned short* hnew_bf = U + 23040000;        // 2,560,000
    unsigned short* Wm1p    = U + 25600000;        // 36,864
    unsigned short* Wm2p    = U + 25636864;        // 16,384
    unsigned short* Wn1p    = U + 25653248;        // 32,768
    unsigned short* Wn2p    = U + 25686016;        // 16,384
    unsigned short* We1p    = U + 25702400;        // 36,864
    unsigned short* Wc1p    = U + 25739264;        // 131,072
    unsigned short* Wrelp   = U + 25870336;        // 131,072
    unsigned short* Wc2p    = U + 26001408;        // 16,384

    // zero: f32 scratch (1,041,024 B) + seg f16 (40,960,000 B), contiguous
    hipMemsetAsync(d_ws, 0, (size_t)260256 * 4 + (size_t)20480000 * 2, stream);

    k_cvt_h<<<2500, 256, 0, stream>>>(h, h_bf);
    k_pack<<<dim3(144, 1), 256, 0, stream>>>(Wm1, Wm1p, 273, 0);
    k_pack<<<dim3(64, 1),  256, 0, stream>>>(Wm2, Wm2p, 128, 0);
    k_pack<<<dim3(128, 1), 256, 0, stream>>>(Wn1, Wn1p, 256, 0);
    k_pack<<<dim3(64, 1),  256, 0, stream>>>(Wn2, Wn2p, 128, 0);
    k_pack<<<dim3(144, 1), 256, 0, stream>>>(We1, We1p, 257, 1);
    k_pack<<<dim3(64, 8),  256, 0, stream>>>(Wc1, Wc1p, 128, 0);
    k_pack<<<dim3(64, 8),  256, 0, stream>>>(Wrel, Wrelp, 128, 0);
    k_pack_wc2<<<dim3(8, 8), 256, 0, stream>>>(Wc2, Wc2p);

    k_norm<<<dim3(RR, 32), 256, 0, stream>>>(coord, edges, nsq);
    k_invnorm<<<1, 128, 0, stream>>>(nsq, inv_norm);
    k_msg<<<dim3(EE / 64, RR), 256, 0, stream>>>(h_bf, coord, eattr, edges, inv_norm,
        Wm1p, bm1, Wm2p, bm2, Wc1p, bc1, Wc2p, sAccum, cnt, seg);
    k_node<<<(NN + 63) / 64, 256, 0, stream>>>(h, h_bf, coord, seg, sAccum, cnt,
        Wrelp, Wn1p, bn1, Wn2p, bn2, out, hnew_bf);
    k_edge<<<dim3(EE / 64, RR), 256, 0, stream>>>(hnew_bf, eattr, edges,
        We1p, be1, We2, be2, out + OUT_M);
}